// Round 7
// baseline (2302.262 us; speedup 1.0000x reference)
//
#include <hip/hip_runtime.h>

typedef __bf16 bf16x8 __attribute__((ext_vector_type(8)));
typedef float f32x4 __attribute__((ext_vector_type(4)));

// ---------------- sizes ----------------
// B=8, LAT=512, CIN=F=256, Hin=Win=64, H=W=128, K=3
// ws layout (bytes):
//   xu_p NHWC bf16 [8][130][130][256] : off 0          size 69222400
//   y1_p NHWC bf16 [8][130][130][256] : off 69222400   size 69222400
//   wm   bf16 [8][256][9][256]        : off 138444800  size 9437184   (reused)
//   sbuf f32 [2][8][256]              : off 147881984  size 16384

#define GLDS(gsrc, ldst) __builtin_amdgcn_global_load_lds( \
    (const __attribute__((address_space(1))) unsigned int*)(gsrc), \
    (__attribute__((address_space(3))) unsigned int*)(ldst), 16, 0, 0)

#define MFMA(a, b, c) __builtin_amdgcn_mfma_f32_16x16x32_bf16((a), (b), (c), 0, 0, 0)

// ---------------- styles ----------------
__global__ void style_kernel(const float* __restrict__ istyle,
                             const float* __restrict__ ws1, const float* __restrict__ bs1,
                             const float* __restrict__ ws2, const float* __restrict__ bs2,
                             float* __restrict__ sbuf) {
    int b = blockIdx.x;
    int which = blockIdx.y;
    int c = threadIdx.x;
    const float* ws = which ? ws2 : ws1;
    const float* bs = which ? bs2 : bs1;
    __shared__ float st[512];
    for (int i = threadIdx.x; i < 512; i += 256) st[i] = istyle[b * 512 + i];
    __syncthreads();
    float acc = bs[c];
    const float* wr = ws + (size_t)c * 512;
    for (int l = 0; l < 512; ++l) acc += st[l] * wr[l];
    sbuf[((size_t)which * 8 + b) * 256 + c] = acc;
}

// ---------------- modulate + demodulate -> bf16 [b][o][tap][c] ----------------
__global__ void modw_kernel(const float* __restrict__ w, const float* __restrict__ s,
                            __bf16* __restrict__ wm) {
    int wv = threadIdx.x >> 6, lane = threadIdx.x & 63;
    int idx = blockIdx.x * 4 + wv;      // 0..2047
    int b = idx >> 8, o = idx & 255;
    int c0 = lane * 4;
    const float* wr = w + ((size_t)o * 256 + c0) * 9;
    const float* sb = s + (size_t)b * 256 + c0;
    float v[36];
    float ss = 0.f;
#pragma unroll
    for (int cc = 0; cc < 4; ++cc) {
        float sm = sb[cc] + 1.0f;
#pragma unroll
        for (int t = 0; t < 9; ++t) {
            float x = wr[cc * 9 + t] * sm;
            v[cc * 9 + t] = x;
            ss += x * x;
        }
    }
#pragma unroll
    for (int off = 32; off > 0; off >>= 1) ss += __shfl_xor(ss, off);
    float d = rsqrtf(ss + 1e-8f);
    __bf16* wp = wm + ((size_t)(b * 256 + o) * 9) * 256 + c0;
#pragma unroll
    for (int t = 0; t < 9; ++t) {
        union { __bf16 h[4]; uint2 u; } pk;
#pragma unroll
        for (int cc = 0; cc < 4; ++cc) pk.h[cc] = (__bf16)(v[cc * 9 + t] * d);
        *(uint2*)(wp + (size_t)t * 256) = pk.u;
    }
}

// ---------------- zero the 1-pixel border ----------------
__global__ void zeropad_kernel(__bf16* __restrict__ xu, __bf16* __restrict__ y1) {
    int p0 = blockIdx.x * 8;
    int b  = blockIdx.y;
    __bf16* buf = blockIdx.z ? y1 : xu;
    int p = p0 + (threadIdx.x >> 5);
    if (p >= 516) return;
    int chunk = threadIdx.x & 31;
    int y, x;
    if (p < 130)      { y = 0;           x = p; }
    else if (p < 260) { y = 129;         x = p - 130; }
    else if (p < 388) { y = p - 260 + 1; x = 0; }
    else              { y = p - 388 + 1; x = 129; }
    uint4 z = make_uint4(0, 0, 0, 0);
    *(uint4*)(buf + (((size_t)b * 130 + y) * 130 + x) * 256 + chunk * 8) = z;
}

// ---------------- bilinear 2x upsample NCHW f32 -> padded NHWC bf16 ----------------
__global__ __launch_bounds__(256) void upsample_kernel(const float* __restrict__ x,
                                                       __bf16* __restrict__ xu) {
    int y = blockIdx.x;   // 0..127
    int b = blockIdx.y;   // 0..7
    __shared__ __bf16 orow[128 * 256];   // [px][ch] 64 KB
    int tid = threadIdx.x;

    int j = y >> 1;
    int y0, y1; float wy0, wy1;
    if (y & 1) { y0 = j; y1 = (j + 1 < 64) ? j + 1 : 63; wy0 = 0.75f; wy1 = 0.25f; }
    else       { y0 = (j - 1 >= 0) ? j - 1 : 0; y1 = j; wy0 = 0.25f; wy1 = 0.75f; }

    int c  = tid >> 3;          // 0..31
    int xs = (tid & 7) * 16;
    for (int ct = 0; ct < 8; ++ct) {
        int cc = ct * 32 + c;
        const float* row0 = x + ((size_t)(b * 256 + cc) * 64 + y0) * 64;
        const float* row1 = x + ((size_t)(b * 256 + cc) * 64 + y1) * 64;
#pragma unroll
        for (int k = 0; k < 16; ++k) {
            int xo = xs + k;
            int i = xo >> 1;
            int x0, x1; float wx0, wx1;
            if (xo & 1) { x0 = i; x1 = (i + 1 < 64) ? i + 1 : 63; wx0 = 0.75f; wx1 = 0.25f; }
            else        { x0 = (i - 1 >= 0) ? i - 1 : 0; x1 = i; wx0 = 0.25f; wx1 = 0.75f; }
            float v0 = wx0 * row0[x0] + wx1 * row0[x1];
            float v1 = wx0 * row1[x0] + wx1 * row1[x1];
            orow[xo * 256 + cc] = (__bf16)(wy0 * v0 + wy1 * v1);
        }
    }
    __syncthreads();
    uint4* dst = (uint4*)(xu + (((size_t)(b * 130) + y + 1) * 130 + 1) * 256);
    const uint4* src = (const uint4*)orow;
#pragma unroll
    for (int it = 0; it < 16; ++it)
        dst[it * 256 + tid] = src[it * 256 + tid];
}

// ---------------- implicit-GEMM modulated conv, 256M x 128N, BK=64, SINGLE buffer ----------------
// Per block: batch b, one output row (128 px), all 256 out-channels.
// 4 waves of 128x64 (acc[8][4]): 24 ds_read_b128 per 64 MFMAs -> 375 B/MFMA.
// SINGLE-buffered LDS 48KB (A 32K + B 16K) -> 3 blocks/CU; blocks are mutually
// unsynchronized so each barrier/fill bubble is covered by another block (m114).
// Per tile: frags->regs (24 ds_read); lgkmcnt(0)+barrier (buffer free); issue 12 GLDS
// for t+1; 64-MFMA cluster hides the stage flight; vmcnt(0)+barrier.
// K-order c0-major/tap-minor (L2-hot staging, R4-verified). XOR-chunk swizzle (0 conflicts).
template <int PHASE>
__global__ __launch_bounds__(256, 3) void conv_kernel(
    const __bf16* __restrict__ in,    // padded NHWC [8][130][130][256]
    const __bf16* __restrict__ wmall, // [8][256][9][256]
    float* __restrict__ outf,
    __bf16* __restrict__ outb) {
    __shared__ __attribute__((aligned(128))) char smem[49152];
    __bf16* const sA = (__bf16*)smem;             // [256][64]
    __bf16* const sB = (__bf16*)(smem + 32768);   // [128][64]
    const int tid  = threadIdx.x;
    const int bid  = blockIdx.x;
    // XCD-bijective swizzle: 1024 blocks = 8 XCDs x 128; one batch per XCD.
    const int swz  = (bid & 7) * 128 + (bid >> 3);
    const int b    = swz >> 7;
    const int yrow = swz & 127;
    const int lane = tid & 63;
    const int wv   = tid >> 6;          // 0..3
    const int wo   = (wv >> 1) * 128;   // wave M offset
    const int wn   = (wv & 1) * 64;     // wave N offset
    const int arow = lane & 15;
    const int cgb  = lane >> 4;         // 0..3
    // staging lane decomposition: 8 rows x 8 chunks per GLDS, source chunk XOR-swizzled
    const int r8     = lane >> 3;
    const int chunkS = (lane & 7) ^ (r8 & 7);
    const __bf16* wm_b = wmall + (size_t)b * 256 * 2304;
    const __bf16* aSrc = wm_b + (size_t)(wv * 64 + r8) * 2304 + chunkS * 8;
    const __bf16* bSrc = in + ((size_t)((b * 130 + yrow) * 130) + wv * 32 + r8) * 256 + chunkS * 8;

    f32x4 acc[8][4] = {};

#define STAGE(tt)                                                             \
    {   const int tap = (tt) % 9, cb = (tt) / 9;                              \
        const int ky = tap / 3, kx = tap - 3 * ky;                            \
        const size_t ao = (size_t)(tap * 256 + cb * 64);                      \
        const size_t bo = (size_t)((ky * 130 + kx) * 256 + cb * 64);          \
        _Pragma("unroll")                                                     \
        for (int q = 0; q < 8; ++q)                                           \
            GLDS(aSrc + ao + (size_t)q * 8 * 2304, sA + (wv * 64 + q * 8) * 64 + lane * 8); \
        _Pragma("unroll")                                                     \
        for (int q = 0; q < 4; ++q)                                           \
            GLDS(bSrc + bo + (size_t)q * 8 * 256,  sB + (wv * 32 + q * 8) * 64 + lane * 8); \
    }

    // prologue: stage tile 0 (tap 0, c0=0)
    STAGE(0);
    asm volatile("s_waitcnt vmcnt(0)" ::: "memory");
    __builtin_amdgcn_s_barrier();
    asm volatile("" ::: "memory");

    for (int t = 0; t < 36; ++t) {
        // read all fragments for tile t into registers
        bf16x8 af[8][2], bfr[4][2];
#pragma unroll
        for (int jj = 0; jj < 4; ++jj) {
            int rb = wn + jj * 16 + arow;
            const char* bp = (const char*)sB + rb * 128;
            bfr[jj][0] = *(const bf16x8*)(bp + ((cgb ^ (rb & 7)) * 16));
            bfr[jj][1] = *(const bf16x8*)(bp + (((cgb + 4) ^ (rb & 7)) * 16));
        }
#pragma unroll
        for (int m = 0; m < 8; ++m) {
            int ra = wo + m * 16 + arow;
            const char* ap = (const char*)sA + ra * 128;
            af[m][0] = *(const bf16x8*)(ap + ((cgb ^ (ra & 7)) * 16));
            af[m][1] = *(const bf16x8*)(ap + (((cgb + 4) ^ (ra & 7)) * 16));
        }
        // all reads retired -> buffer free for overwrite
        asm volatile("s_waitcnt lgkmcnt(0)" ::: "memory");
        __builtin_amdgcn_sched_barrier(0);
        __builtin_amdgcn_s_barrier();
        asm volatile("" ::: "memory");
        // issue next tile's staging; lands during the MFMA cluster below
        if (t < 35) STAGE(t + 1);
        __builtin_amdgcn_s_setprio(1);
#pragma unroll
        for (int m = 0; m < 8; ++m)
#pragma unroll
            for (int jj = 0; jj < 4; ++jj) {
                acc[m][jj] = MFMA(af[m][0], bfr[jj][0], acc[m][jj]);
                acc[m][jj] = MFMA(af[m][1], bfr[jj][1], acc[m][jj]);
            }
        __builtin_amdgcn_s_setprio(0);
        asm volatile("s_waitcnt vmcnt(0)" ::: "memory");
        __builtin_amdgcn_s_barrier();
        asm volatile("" ::: "memory");
    }
#undef STAGE

    // pin all pending LDS ops before reusing smem (rule #18)
    __builtin_amdgcn_sched_barrier(0);
    __syncthreads();

    if (PHASE == 1) {
        // 2-pass: px-half -> LDS [64][512B] (32KB), XOR-swizzled, then contiguous flush
        __bf16* const ot = (__bf16*)smem;
#pragma unroll
        for (int p = 0; p < 2; ++p) {
            if ((wv & 1) == p) {
#pragma unroll
                for (int m = 0; m < 8; ++m)
#pragma unroll
                    for (int jj = 0; jj < 4; ++jj) {
                        int pxl = jj * 16 + arow;                 // 0..63
                        int ob  = (wo + m * 16 + cgb * 4) * 2;    // byte in 512B row
                        union { __bf16 v[4]; uint2 u; } pk;
#pragma unroll
                        for (int r = 0; r < 4; ++r) {
                            float v = acc[m][jj][r];
                            pk.v[r] = (__bf16)((v > 0.f) ? v : 0.2f * v);
                        }
                        *(uint2*)((char*)ot + pxl * 512 + (ob ^ ((pxl & 7) << 4))) = pk.u;
                    }
            }
            __syncthreads();
#pragma unroll
            for (int it = 0; it < 8; ++it) {
                int n  = it * 8 + (tid >> 5);
                int px = p * 64 + n;
                uint4 v = *(const uint4*)((const char*)ot + n * 512 + (((tid & 31) * 16) ^ ((n & 7) << 4)));
                *(uint4*)(outb + (((size_t)(b * 130) + yrow + 1) * 130 + px + 1) * 256 + (tid & 31) * 8) = v;
            }
            if (p == 0) __syncthreads();
        }
    } else {
        // NCHW f32: 16 lanes x 4B = contiguous 64B lines
#pragma unroll
        for (int m = 0; m < 8; ++m)
#pragma unroll
            for (int jj = 0; jj < 4; ++jj) {
                int o_base = wo + m * 16 + (lane >> 4) * 4;
                int n      = wn + jj * 16 + (lane & 15);
#pragma unroll
                for (int r = 0; r < 4; ++r) {
                    float v = acc[m][jj][r];
                    v = (v > 0.f) ? v : 0.2f * v;
                    outf[((size_t)(b * 256 + o_base + r) * 128 + yrow) * 128 + n] = v;
                }
            }
    }
}

extern "C" void kernel_launch(void* const* d_in, const int* in_sizes, int n_in,
                              void* d_out, int out_size, void* d_ws, size_t ws_size,
                              hipStream_t stream) {
    const float* x      = (const float*)d_in[0];
    const float* istyle = (const float*)d_in[1];
    const float* ws1    = (const float*)d_in[2];
    const float* bs1    = (const float*)d_in[3];
    const float* w1     = (const float*)d_in[4];
    const float* ws2    = (const float*)d_in[5];
    const float* bs2    = (const float*)d_in[6];
    const float* w2     = (const float*)d_in[7];
    float* out = (float*)d_out;

    char* ws = (char*)d_ws;
    __bf16* xu_p = (__bf16*)(ws);
    __bf16* y1_p = (__bf16*)(ws + 69222400);
    __bf16* wm   = (__bf16*)(ws + 138444800);
    float*  sbuf = (float*)(ws + 147881984);

    style_kernel<<<dim3(8, 2), 256, 0, stream>>>(istyle, ws1, bs1, ws2, bs2, sbuf);
    zeropad_kernel<<<dim3(65, 8, 2), 256, 0, stream>>>(xu_p, y1_p);
    upsample_kernel<<<dim3(128, 8), 256, 0, stream>>>(x, xu_p);
    modw_kernel<<<dim3(512), 256, 0, stream>>>(w1, sbuf, wm);
    conv_kernel<1><<<dim3(1024), 256, 0, stream>>>(xu_p, wm, nullptr, y1_p);
    modw_kernel<<<dim3(512), 256, 0, stream>>>(w2, sbuf + 2048, wm);
    conv_kernel<2><<<dim3(1024), 256, 0, stream>>>(y1_p, wm, out, nullptr);
}

// Round 8
// 722.265 us; speedup vs baseline: 3.1876x; 3.1876x over previous
//
#include <hip/hip_runtime.h>

typedef __bf16 bf16x8 __attribute__((ext_vector_type(8)));
typedef float f32x16 __attribute__((ext_vector_type(16)));

// ---------------- sizes ----------------
// B=8, LAT=512, CIN=F=256, Hin=Win=64, H=W=128, K=3
// ws layout (bytes):
//   xu_p NHWC bf16 [8][130][130][256] : off 0          size 69222400
//   y1_p NHWC bf16 [8][130][130][256] : off 69222400   size 69222400
//   wm   bf16 [8][256][9][256]        : off 138444800  size 9437184   (reused)
//   sbuf f32 [2][8][256]              : off 147881984  size 16384

#define GLDS(gsrc, ldst) __builtin_amdgcn_global_load_lds( \
    (const __attribute__((address_space(1))) unsigned int*)(gsrc), \
    (__attribute__((address_space(3))) unsigned int*)(ldst), 16, 0, 0)

#define MFMA32(a, b, c) __builtin_amdgcn_mfma_f32_32x32x16_bf16((a), (b), (c), 0, 0, 0)

// ---------------- styles ----------------
__global__ void style_kernel(const float* __restrict__ istyle,
                             const float* __restrict__ ws1, const float* __restrict__ bs1,
                             const float* __restrict__ ws2, const float* __restrict__ bs2,
                             float* __restrict__ sbuf) {
    int b = blockIdx.x;
    int which = blockIdx.y;
    int c = threadIdx.x;
    const float* ws = which ? ws2 : ws1;
    const float* bs = which ? bs2 : bs1;
    __shared__ float st[512];
    for (int i = threadIdx.x; i < 512; i += 256) st[i] = istyle[b * 512 + i];
    __syncthreads();
    float acc = bs[c];
    const float* wr = ws + (size_t)c * 512;
    for (int l = 0; l < 512; ++l) acc += st[l] * wr[l];
    sbuf[((size_t)which * 8 + b) * 256 + c] = acc;
}

// ---------------- modulate + demodulate -> bf16 [b][o][tap][c] ----------------
__global__ void modw_kernel(const float* __restrict__ w, const float* __restrict__ s,
                            __bf16* __restrict__ wm) {
    int wv = threadIdx.x >> 6, lane = threadIdx.x & 63;
    int idx = blockIdx.x * 4 + wv;      // 0..2047
    int b = idx >> 8, o = idx & 255;
    int c0 = lane * 4;
    const float* wr = w + ((size_t)o * 256 + c0) * 9;
    const float* sb = s + (size_t)b * 256 + c0;
    float v[36];
    float ss = 0.f;
#pragma unroll
    for (int cc = 0; cc < 4; ++cc) {
        float sm = sb[cc] + 1.0f;
#pragma unroll
        for (int t = 0; t < 9; ++t) {
            float x = wr[cc * 9 + t] * sm;
            v[cc * 9 + t] = x;
            ss += x * x;
        }
    }
#pragma unroll
    for (int off = 32; off > 0; off >>= 1) ss += __shfl_xor(ss, off);
    float d = rsqrtf(ss + 1e-8f);
    __bf16* wp = wm + ((size_t)(b * 256 + o) * 9) * 256 + c0;
#pragma unroll
    for (int t = 0; t < 9; ++t) {
        union { __bf16 h[4]; uint2 u; } pk;
#pragma unroll
        for (int cc = 0; cc < 4; ++cc) pk.h[cc] = (__bf16)(v[cc * 9 + t] * d);
        *(uint2*)(wp + (size_t)t * 256) = pk.u;
    }
}

// ---------------- zero the 1-pixel border ----------------
__global__ void zeropad_kernel(__bf16* __restrict__ xu, __bf16* __restrict__ y1) {
    int p0 = blockIdx.x * 8;
    int b  = blockIdx.y;
    __bf16* buf = blockIdx.z ? y1 : xu;
    int p = p0 + (threadIdx.x >> 5);
    if (p >= 516) return;
    int chunk = threadIdx.x & 31;
    int y, x;
    if (p < 130)      { y = 0;           x = p; }
    else if (p < 260) { y = 129;         x = p - 130; }
    else if (p < 388) { y = p - 260 + 1; x = 0; }
    else              { y = p - 388 + 1; x = 129; }
    uint4 z = make_uint4(0, 0, 0, 0);
    *(uint4*)(buf + (((size_t)b * 130 + y) * 130 + x) * 256 + chunk * 8) = z;
}

// ---------------- bilinear 2x upsample NCHW f32 -> padded NHWC bf16 ----------------
__global__ __launch_bounds__(256) void upsample_kernel(const float* __restrict__ x,
                                                       __bf16* __restrict__ xu) {
    int y = blockIdx.x;   // 0..127
    int b = blockIdx.y;   // 0..7
    __shared__ __bf16 orow[128 * 256];   // [px][ch] 64 KB
    int tid = threadIdx.x;

    int j = y >> 1;
    int y0, y1; float wy0, wy1;
    if (y & 1) { y0 = j; y1 = (j + 1 < 64) ? j + 1 : 63; wy0 = 0.75f; wy1 = 0.25f; }
    else       { y0 = (j - 1 >= 0) ? j - 1 : 0; y1 = j; wy0 = 0.25f; wy1 = 0.75f; }

    int c  = tid >> 3;          // 0..31
    int xs = (tid & 7) * 16;
    for (int ct = 0; ct < 8; ++ct) {
        int cc = ct * 32 + c;
        const float* row0 = x + ((size_t)(b * 256 + cc) * 64 + y0) * 64;
        const float* row1 = x + ((size_t)(b * 256 + cc) * 64 + y1) * 64;
#pragma unroll
        for (int k = 0; k < 16; ++k) {
            int xo = xs + k;
            int i = xo >> 1;
            int x0, x1; float wx0, wx1;
            if (xo & 1) { x0 = i; x1 = (i + 1 < 64) ? i + 1 : 63; wx0 = 0.75f; wx1 = 0.25f; }
            else        { x0 = (i - 1 >= 0) ? i - 1 : 0; x1 = i; wx0 = 0.25f; wx1 = 0.75f; }
            float v0 = wx0 * row0[x0] + wx1 * row0[x1];
            float v1 = wx0 * row1[x0] + wx1 * row1[x1];
            orow[xo * 256 + cc] = (__bf16)(wy0 * v0 + wy1 * v1);
        }
    }
    __syncthreads();
    uint4* dst = (uint4*)(xu + (((size_t)(b * 130) + y + 1) * 130 + 1) * 256);
    const uint4* src = (const uint4*)orow;
#pragma unroll
    for (int it = 0; it < 16; ++it)
        dst[it * 256 + tid] = src[it * 256 + tid];
}

// ---------------- implicit-GEMM modulated conv: A-in-LDS, B-direct, 32x32x16 ----------------
// Per block: batch b, one output row (128 px), 128 out-channels (mtile om).
// 4 waves of 64M x 64N: acc[2][2] f32x16 (64 regs). BK=64 -> 36 K-tiles, c0-major/tap-minor.
// A (weights) LDS double-buffered [2][128][64] = 32 KB; B (input) loaded DIRECTLY from
// global to regs (L1-resident across the 9 taps of a c0-band) -> LDS traffic ~halved,
// 3 blocks/CU (launch_bounds 256,3; regs ~140 incl 64-acc).  One barrier per K-tile.
// A XOR-chunk swizzle verified (stage chunkS = (lane&7)^(r8&7); read chunk ^ (row&7)).
template <int PHASE>
__global__ __launch_bounds__(256, 3) void conv_kernel(
    const __bf16* __restrict__ in,    // padded NHWC [8][130][130][256]
    const __bf16* __restrict__ wmall, // [8][256][9][256]
    float* __restrict__ outf,
    __bf16* __restrict__ outb) {
    __shared__ __attribute__((aligned(128))) char smem[32768];  // A dbuf [2][128][64] bf16
    const int tid  = threadIdx.x;
    const int bid  = blockIdx.x;
    // XCD-bijective swizzle: 2048 blocks = 8 XCDs x 256; one batch per XCD (both mtiles).
    const int swz  = (bid & 7) * 256 + (bid >> 3);
    const int b    = swz >> 8;
    const int rem  = swz & 255;
    const int yrow = rem >> 1;
    const int om   = (rem & 1) * 128;
    const int lane = tid & 63;
    const int wv   = tid >> 6;          // 0..3
    const int wo   = (wv >> 1) * 64;    // wave M offset within 128
    const int wn   = (wv & 1) * 64;     // wave N offset within 128
    const int l31  = lane & 31;
    const int hi   = lane >> 5;         // k-group
    // A staging: per wave stages rows wv*32..wv*32+31; 4 GLDS x 8 rows
    const int r8     = lane >> 3;
    const int chunkS = (lane & 7) ^ (r8 & 7);
    const __bf16* aSrc = wmall + ((size_t)(b * 256 + om + wv * 32 + r8)) * 2304 + chunkS * 8;
    // B lane base: pixel = wn + l31 (+ j*32 + kx), channel = c0 + s*16 + hi*8
    const __bf16* bLane = in + ((size_t)((b * 130 + yrow) * 130) + wn + l31) * 256 + hi * 8;
    // A fragment read base (bytes within buffer): row = wo + mi*32 + l31
    const int aReadBase = (wo + l31) * 128 + ((hi ^ (lane & 7)) * 16);

    f32x16 acc[2][2] = {};

    // prologue: stage A tile 0 (tap 0, c0=0) into buf 0
    {
        __bf16* Ad = (__bf16*)smem + (wv * 32) * 64;
#pragma unroll
        for (int q = 0; q < 4; ++q)
            GLDS(aSrc + (size_t)q * 8 * 2304, Ad + q * 8 * 64);
    }
    asm volatile("s_waitcnt vmcnt(0)" ::: "memory");
    __builtin_amdgcn_s_barrier();
    asm volatile("" ::: "memory");

    for (int t = 0; t < 36; ++t) {
        const int cb  = t / 9;
        const int tap = t - 9 * cb;
        const int ky  = tap / 3, kx = tap - 3 * ky;
        // B loads for tile t, direct to regs (L1-hot: same pixel lines across taps)
        const __bf16* Bt = bLane + (size_t)((ky * 130 + kx) * 256 + cb * 64);
        bf16x8 bfr[4][2];
#pragma unroll
        for (int s = 0; s < 4; ++s)
#pragma unroll
            for (int j = 0; j < 2; ++j)
                bfr[s][j] = *(const bf16x8*)(Bt + j * 32 * 256 + s * 16);
        // stage A(t+1) into the other buffer
        if (t < 35) {
            const int nt = t + 1;
            const int ncb = nt / 9;
            const int ntap = nt - 9 * ncb;
            const __bf16* As = aSrc + (size_t)(ntap * 256 + ncb * 64);
            __bf16* Ad = (__bf16*)smem + ((nt & 1) * 8192) + (wv * 32) * 64;
#pragma unroll
            for (int q = 0; q < 4; ++q)
                GLDS(As + (size_t)q * 8 * 2304, Ad + q * 8 * 64);
        }
        // compute: 16 MFMA(32x32x16)
        const char* Ab = smem + (t & 1) * 16384;
        __builtin_amdgcn_s_setprio(1);
#pragma unroll
        for (int s = 0; s < 4; ++s) {
            const int cs = aReadBase ^ (s << 5);
            bf16x8 a0 = *(const bf16x8*)(Ab + cs);
            bf16x8 a1 = *(const bf16x8*)(Ab + cs + 4096);
            acc[0][0] = MFMA32(a0, bfr[s][0], acc[0][0]);
            acc[0][1] = MFMA32(a0, bfr[s][1], acc[0][1]);
            acc[1][0] = MFMA32(a1, bfr[s][0], acc[1][0]);
            acc[1][1] = MFMA32(a1, bfr[s][1], acc[1][1]);
        }
        __builtin_amdgcn_s_setprio(0);
        asm volatile("s_waitcnt vmcnt(0)" ::: "memory");
        __builtin_amdgcn_s_barrier();
        asm volatile("" ::: "memory");
    }

    // pin all pending LDS ops before reusing smem (rule #18)
    __builtin_amdgcn_sched_barrier(0);
    __syncthreads();

    // C/D layout (32x32, m74/m101): col = lane&31, row = (reg&3) + 8*(reg>>2) + 4*(lane>>5)
    if (PHASE == 1) {
        // stage [128 px][128 och] bf16 (32 KB) into LDS, XOR-swizzled; flush contiguous
        __bf16* const ot = (__bf16*)smem;
#pragma unroll
        for (int mi = 0; mi < 2; ++mi)
#pragma unroll
            for (int j = 0; j < 2; ++j) {
                int px = wn + j * 32 + l31;
#pragma unroll
                for (int q2 = 0; q2 < 4; ++q2) {
                    int ob = (wo + mi * 32 + 8 * q2 + 4 * hi) * 2;  // byte in 256B row
                    union { __bf16 v[4]; uint2 u; } pk;
#pragma unroll
                    for (int r = 0; r < 4; ++r) {
                        float v = acc[mi][j][q2 * 4 + r];
                        pk.v[r] = (__bf16)((v > 0.f) ? v : 0.2f * v);
                    }
                    *(uint2*)((char*)ot + px * 256 + (ob ^ ((px & 7) << 4))) = pk.u;
                }
            }
        __syncthreads();
        // flush: 4 px per instr, 16 lanes x 16B = 256B contiguous per pixel
#pragma unroll
        for (int it = 0; it < 8; ++it) {
            int px = wv * 32 + it * 4 + (lane >> 4);
            uint4 v = *(const uint4*)((const char*)ot + px * 256 + (((lane & 15) * 16) ^ ((px & 7) << 4)));
            *(uint4*)(outb + (((size_t)(b * 130) + yrow + 1) * 130 + px + 1) * 256 + om + (lane & 15) * 8) = v;
        }
    } else {
        // NCHW f32: 32 lanes x 4B = contiguous 128B per (och) row
#pragma unroll
        for (int mi = 0; mi < 2; ++mi)
#pragma unroll
            for (int j = 0; j < 2; ++j) {
                int n = wn + j * 32 + l31;
#pragma unroll
                for (int q2 = 0; q2 < 4; ++q2)
#pragma unroll
                    for (int r = 0; r < 4; ++r) {
                        int och = om + wo + mi * 32 + 8 * q2 + 4 * hi + r;
                        float v = acc[mi][j][q2 * 4 + r];
                        v = (v > 0.f) ? v : 0.2f * v;
                        outf[((size_t)(b * 256 + och) * 128 + yrow) * 128 + n] = v;
                    }
            }
    }
}

extern "C" void kernel_launch(void* const* d_in, const int* in_sizes, int n_in,
                              void* d_out, int out_size, void* d_ws, size_t ws_size,
                              hipStream_t stream) {
    const float* x      = (const float*)d_in[0];
    const float* istyle = (const float*)d_in[1];
    const float* ws1    = (const float*)d_in[2];
    const float* bs1    = (const float*)d_in[3];
    const float* w1     = (const float*)d_in[4];
    const float* ws2    = (const float*)d_in[5];
    const float* bs2    = (const float*)d_in[6];
    const float* w2     = (const float*)d_in[7];
    float* out = (float*)d_out;

    char* ws = (char*)d_ws;
    __bf16* xu_p = (__bf16*)(ws);
    __bf16* y1_p = (__bf16*)(ws + 69222400);
    __bf16* wm   = (__bf16*)(ws + 138444800);
    float*  sbuf = (float*)(ws + 147881984);

    style_kernel<<<dim3(8, 2), 256, 0, stream>>>(istyle, ws1, bs1, ws2, bs2, sbuf);
    zeropad_kernel<<<dim3(65, 8, 2), 256, 0, stream>>>(xu_p, y1_p);
    upsample_kernel<<<dim3(128, 8), 256, 0, stream>>>(x, xu_p);
    modw_kernel<<<dim3(512), 256, 0, stream>>>(w1, sbuf, wm);
    conv_kernel<1><<<dim3(2048), 256, 0, stream>>>(xu_p, wm, nullptr, y1_p);
    modw_kernel<<<dim3(512), 256, 0, stream>>>(w2, sbuf + 2048, wm);
    conv_kernel<2><<<dim3(2048), 256, 0, stream>>>(y1_p, wm, out, nullptr);
}

// Round 9
// 427.568 us; speedup vs baseline: 5.3846x; 1.6892x over previous
//
#include <hip/hip_runtime.h>

typedef __bf16 bf16x8 __attribute__((ext_vector_type(8)));
typedef float f32x4 __attribute__((ext_vector_type(4)));

// ---------------- sizes ----------------
// B=8, LAT=512, CIN=F=256, Hin=Win=64, H=W=128, K=3
// ws layout (bytes):
//   xu_p NHWC bf16 [8][130][130][256] : off 0          size 69222400
//   y1_p NHWC bf16 [8][130][130][256] : off 69222400   size 69222400
//   wm   bf16 [8][256][9][256]        : off 138444800  size 9437184   (reused)
//   sbuf f32 [2][8][256]              : off 147881984  size 16384

#define GLDS(gsrc, ldst) __builtin_amdgcn_global_load_lds( \
    (const __attribute__((address_space(1))) unsigned int*)(gsrc), \
    (__attribute__((address_space(3))) unsigned int*)(ldst), 16, 0, 0)

#define MFMA(a, b, c) __builtin_amdgcn_mfma_f32_16x16x32_bf16((a), (b), (c), 0, 0, 0)

// ---------------- styles ----------------
__global__ void style_kernel(const float* __restrict__ istyle,
                             const float* __restrict__ ws1, const float* __restrict__ bs1,
                             const float* __restrict__ ws2, const float* __restrict__ bs2,
                             float* __restrict__ sbuf) {
    int b = blockIdx.x;
    int which = blockIdx.y;
    int c = threadIdx.x;
    const float* ws = which ? ws2 : ws1;
    const float* bs = which ? bs2 : bs1;
    __shared__ float st[512];
    for (int i = threadIdx.x; i < 512; i += 256) st[i] = istyle[b * 512 + i];
    __syncthreads();
    float acc = bs[c];
    const float* wr = ws + (size_t)c * 512;
    for (int l = 0; l < 512; ++l) acc += st[l] * wr[l];
    sbuf[((size_t)which * 8 + b) * 256 + c] = acc;
}

// ---------------- modulate + demodulate -> bf16 [b][o][tap][c] ----------------
__global__ void modw_kernel(const float* __restrict__ w, const float* __restrict__ s,
                            __bf16* __restrict__ wm) {
    int wv = threadIdx.x >> 6, lane = threadIdx.x & 63;
    int idx = blockIdx.x * 4 + wv;      // 0..2047
    int b = idx >> 8, o = idx & 255;
    int c0 = lane * 4;
    const float* wr = w + ((size_t)o * 256 + c0) * 9;
    const float* sb = s + (size_t)b * 256 + c0;
    float v[36];
    float ss = 0.f;
#pragma unroll
    for (int cc = 0; cc < 4; ++cc) {
        float sm = sb[cc] + 1.0f;
#pragma unroll
        for (int t = 0; t < 9; ++t) {
            float x = wr[cc * 9 + t] * sm;
            v[cc * 9 + t] = x;
            ss += x * x;
        }
    }
#pragma unroll
    for (int off = 32; off > 0; off >>= 1) ss += __shfl_xor(ss, off);
    float d = rsqrtf(ss + 1e-8f);
    __bf16* wp = wm + ((size_t)(b * 256 + o) * 9) * 256 + c0;
#pragma unroll
    for (int t = 0; t < 9; ++t) {
        union { __bf16 h[4]; uint2 u; } pk;
#pragma unroll
        for (int cc = 0; cc < 4; ++cc) pk.h[cc] = (__bf16)(v[cc * 9 + t] * d);
        *(uint2*)(wp + (size_t)t * 256) = pk.u;
    }
}

// ---------------- zero the 1-pixel border ----------------
__global__ void zeropad_kernel(__bf16* __restrict__ xu, __bf16* __restrict__ y1) {
    int p0 = blockIdx.x * 8;
    int b  = blockIdx.y;
    __bf16* buf = blockIdx.z ? y1 : xu;
    int p = p0 + (threadIdx.x >> 5);
    if (p >= 516) return;
    int chunk = threadIdx.x & 31;
    int y, x;
    if (p < 130)      { y = 0;           x = p; }
    else if (p < 260) { y = 129;         x = p - 130; }
    else if (p < 388) { y = p - 260 + 1; x = 0; }
    else              { y = p - 388 + 1; x = 129; }
    uint4 z = make_uint4(0, 0, 0, 0);
    *(uint4*)(buf + (((size_t)b * 130 + y) * 130 + x) * 256 + chunk * 8) = z;
}

// ---------------- bilinear 2x upsample NCHW f32 -> padded NHWC bf16 ----------------
__global__ __launch_bounds__(256) void upsample_kernel(const float* __restrict__ x,
                                                       __bf16* __restrict__ xu) {
    int y = blockIdx.x;   // 0..127
    int b = blockIdx.y;   // 0..7
    __shared__ __bf16 orow[128 * 256];   // [px][ch] 64 KB
    int tid = threadIdx.x;

    int j = y >> 1;
    int y0, y1; float wy0, wy1;
    if (y & 1) { y0 = j; y1 = (j + 1 < 64) ? j + 1 : 63; wy0 = 0.75f; wy1 = 0.25f; }
    else       { y0 = (j - 1 >= 0) ? j - 1 : 0; y1 = j; wy0 = 0.25f; wy1 = 0.75f; }

    int c  = tid >> 3;          // 0..31
    int xs = (tid & 7) * 16;
    for (int ct = 0; ct < 8; ++ct) {
        int cc = ct * 32 + c;
        const float* row0 = x + ((size_t)(b * 256 + cc) * 64 + y0) * 64;
        const float* row1 = x + ((size_t)(b * 256 + cc) * 64 + y1) * 64;
#pragma unroll
        for (int k = 0; k < 16; ++k) {
            int xo = xs + k;
            int i = xo >> 1;
            int x0, x1; float wx0, wx1;
            if (xo & 1) { x0 = i; x1 = (i + 1 < 64) ? i + 1 : 63; wx0 = 0.75f; wx1 = 0.25f; }
            else        { x0 = (i - 1 >= 0) ? i - 1 : 0; x1 = i; wx0 = 0.25f; wx1 = 0.75f; }
            float v0 = wx0 * row0[x0] + wx1 * row0[x1];
            float v1 = wx0 * row1[x0] + wx1 * row1[x1];
            orow[xo * 256 + cc] = (__bf16)(wy0 * v0 + wy1 * v1);
        }
    }
    __syncthreads();
    uint4* dst = (uint4*)(xu + (((size_t)(b * 130) + y + 1) * 130 + 1) * 256);
    const uint4* src = (const uint4*)orow;
#pragma unroll
    for (int it = 0; it < 16; ++it)
        dst[it * 256 + tid] = src[it * 256 + tid];
}

// ---------------- implicit-GEMM modulated conv: 256Mx128N, BK=32, TRIPLE buffer ----------------
// Per block: batch b, one output row (128 px), all 256 out-channels.
// 4 waves of 128x64 (acc[8][4] = 128 VGPR): LDS bytes/FLOP = 0.035 -> LDS no longer the cap.
// LDS = 3 bufs x (A [256][32] 16KB + B [128][32] 8KB) = 72KB -> 2 independent blocks/CU.
// Counted vmcnt (T4): STAGE(t+2) issued at tile t; end-of-tile vmcnt(6) waits only t+1's
// 6 loads (2-tile slack ~1200cy >> L2 latency) - never drains the pipeline.
// Per tile: 12 ds_read -> lgkmcnt(0)+barrier (read-protect) -> 6 GLDS -> 32 MFMA
// -> vmcnt(6)+barrier.  Swizzle for 64B rows: LDS[r][c16] = g[r][c16 ^ ((r>>1)&3)];
// 8-lane read groups hit 8 distinct bank-quads (conflict-free).
// K-order c0-major/tap-minor (L2-hot staging, R4-verified: FETCH 44MB).
template <int PHASE>
__global__ __launch_bounds__(256, 2) void conv_kernel(
    const __bf16* __restrict__ in,    // padded NHWC [8][130][130][256]
    const __bf16* __restrict__ wmall, // [8][256][9][256]
    float* __restrict__ outf,
    __bf16* __restrict__ outb) {
    __shared__ __attribute__((aligned(128))) char smem[73728];  // 3 x 24576
    const int tid  = threadIdx.x;
    const int bid  = blockIdx.x;
    // XCD-bijective swizzle: 1024 blocks = 8 XCDs x 128; one batch per XCD.
    const int swz  = (bid & 7) * 128 + (bid >> 3);
    const int b    = swz >> 7;
    const int yrow = swz & 127;
    const int lane = tid & 63;
    const int wv   = tid >> 6;          // 0..3
    const int wo   = (wv >> 1) * 128;   // wave M offset (0/128)
    const int wn   = (wv & 1) * 64;     // wave N offset (0/64)
    const int arow = lane & 15;
    const int cg   = lane >> 4;         // 0..3 (16B k-chunk within BK=32)
    const int swR  = (cg ^ ((arow >> 1) & 3)) << 4;   // read-side swizzled chunk byte
    // staging lane decomposition: 16 rows x 4 chunks per GLDS, source chunk pre-swizzled
    const int r16    = lane >> 2;                       // 0..15 row within 16-row slab
    const int chunkS = (lane & 3) ^ ((lane >> 3) & 3);  // source 16B chunk
    const __bf16* aSrc = wmall + ((size_t)b * 256 + wv * 64 + r16) * 2304 + chunkS * 8;
    const __bf16* bSrc = in + ((size_t)((b * 130 + yrow) * 130) + wv * 32 + r16) * 256 + chunkS * 8;

    f32x4 acc[8][4] = {};

    // STAGE tile tt into buffer bsel: A 4 GLDS (64 rows/wave), B 2 GLDS (32 rows/wave)
#define STAGE(tt, bsel)                                                         \
    {   const int tap_ = (tt) % 9, cb_ = (tt) / 9;                              \
        const size_t ao_ = (size_t)(tap_ * 256 + cb_ * 32);                     \
        const size_t bo_ = (size_t)(((tap_ / 3) * 130 + (tap_ % 3)) * 256 + cb_ * 32); \
        __bf16* Ad_ = (__bf16*)(smem + (bsel) * 24576) + (wv * 64) * 32;        \
        __bf16* Bd_ = (__bf16*)(smem + (bsel) * 24576 + 16384) + (wv * 32) * 32; \
        _Pragma("unroll")                                                       \
        for (int q = 0; q < 4; ++q)                                             \
            GLDS(aSrc + ao_ + (size_t)q * 16 * 2304, Ad_ + q * 16 * 32);        \
        _Pragma("unroll")                                                       \
        for (int q = 0; q < 2; ++q)                                             \
            GLDS(bSrc + bo_ + (size_t)q * 16 * 256,  Bd_ + q * 16 * 32);        \
    }

    // prologue: stage tiles 0 and 1
    STAGE(0, 0);
    STAGE(1, 1);
    asm volatile("s_waitcnt vmcnt(6)" ::: "memory");   // tile 0 landed (tile 1 in flight)
    __builtin_amdgcn_s_barrier();
    asm volatile("" ::: "memory");

    for (int t = 0; t < 72; ++t) {
        const int bsel = t % 3;
        const char* Ab = smem + bsel * 24576;
        const char* Bb = Ab + 16384;
        // read all fragments for tile t into registers (12 ds_read_b128)
        bf16x8 af[8], bfr[4];
#pragma unroll
        for (int jj = 0; jj < 4; ++jj)
            bfr[jj] = *(const bf16x8*)(Bb + (wn + jj * 16 + arow) * 64 + swR);
#pragma unroll
        for (int m = 0; m < 8; ++m)
            af[m] = *(const bf16x8*)(Ab + (wo + m * 16 + arow) * 64 + swR);
        // reads retired -> safe for anyone to overwrite buf[t%3] after the barrier
        asm volatile("s_waitcnt lgkmcnt(0)" ::: "memory");
        __builtin_amdgcn_sched_barrier(0);
        __builtin_amdgcn_s_barrier();
        asm volatile("" ::: "memory");
        // stage tile t+2 into buf[(t+2)%3] (= buf[(t-1)%3], last read at t-1: safe)
        if (t < 70) STAGE(t + 2, (t + 2) % 3);
        __builtin_amdgcn_s_setprio(1);
#pragma unroll
        for (int m = 0; m < 8; ++m)
#pragma unroll
            for (int jj = 0; jj < 4; ++jj)
                acc[m][jj] = MFMA(af[m], bfr[jj], acc[m][jj]);
        __builtin_amdgcn_s_setprio(0);
        // counted wait: ensure tile t+1 landed; keep t+2's 6 loads in flight
        if (t < 70)      { asm volatile("s_waitcnt vmcnt(6)" ::: "memory"); }
        else if (t == 70){ asm volatile("s_waitcnt vmcnt(0)" ::: "memory"); }
        if (t < 71) {
            __builtin_amdgcn_s_barrier();
            asm volatile("" ::: "memory");
        }
    }
#undef STAGE

    // pin all pending LDS ops before reusing smem (rule #18)
    __builtin_amdgcn_sched_barrier(0);
    __syncthreads();

    if (PHASE == 1) {
        // stage output tile [128 px][256 och] bf16 (64 KB) into LDS, XOR-swizzled rows
        __bf16* const ot = (__bf16*)smem;
#pragma unroll
        for (int m = 0; m < 8; ++m)
#pragma unroll
            for (int jj = 0; jj < 4; ++jj) {
                int n  = wn + jj * 16 + arow;
                int ob = (wo + m * 16 + cg * 4) * 2;   // byte offset within 512B row
                union { __bf16 v[4]; uint2 u; } pk;
#pragma unroll
                for (int r = 0; r < 4; ++r) {
                    float v = acc[m][jj][r];
                    pk.v[r] = (__bf16)((v > 0.f) ? v : 0.2f * v);
                }
                *(uint2*)((char*)ot + n * 512 + (ob ^ ((n & 7) << 4))) = pk.u;
            }
        __syncthreads();
        // flush: 2 px per instr, 32 lanes x 16B = contiguous 512B per pixel
        const int half = lane >> 5;
        const int l32  = lane & 31;
#pragma unroll
        for (int it = 0; it < 16; ++it) {
            int n = wv * 32 + it * 2 + half;
            uint4 v = *(const uint4*)((const char*)ot + n * 512 + ((l32 * 16) ^ ((n & 7) << 4)));
            *(uint4*)(outb + (((size_t)(b * 130) + yrow + 1) * 130 + n + 1) * 256 + l32 * 8) = v;
        }
    } else {
        // NCHW f32: 16 lanes x 4B = contiguous 64B lines
#pragma unroll
        for (int m = 0; m < 8; ++m)
#pragma unroll
            for (int jj = 0; jj < 4; ++jj) {
                int o_base = wo + m * 16 + cg * 4;
                int n      = wn + jj * 16 + arow;
#pragma unroll
                for (int r = 0; r < 4; ++r) {
                    float v = acc[m][jj][r];
                    v = (v > 0.f) ? v : 0.2f * v;
                    outf[((size_t)(b * 256 + o_base + r) * 128 + yrow) * 128 + n] = v;
                }
            }
    }
}

extern "C" void kernel_launch(void* const* d_in, const int* in_sizes, int n_in,
                              void* d_out, int out_size, void* d_ws, size_t ws_size,
                              hipStream_t stream) {
    const float* x      = (const float*)d_in[0];
    const float* istyle = (const float*)d_in[1];
    const float* ws1    = (const float*)d_in[2];
    const float* bs1    = (const float*)d_in[3];
    const float* w1     = (const float*)d_in[4];
    const float* ws2    = (const float*)d_in[5];
    const float* bs2    = (const float*)d_in[6];
    const float* w2     = (const float*)d_in[7];
    float* out = (float*)d_out;

    char* ws = (char*)d_ws;
    __bf16* xu_p = (__bf16*)(ws);
    __bf16* y1_p = (__bf16*)(ws + 69222400);
    __bf16* wm   = (__bf16*)(ws + 138444800);
    float*  sbuf = (float*)(ws + 147881984);

    style_kernel<<<dim3(8, 2), 256, 0, stream>>>(istyle, ws1, bs1, ws2, bs2, sbuf);
    zeropad_kernel<<<dim3(65, 8, 2), 256, 0, stream>>>(xu_p, y1_p);
    upsample_kernel<<<dim3(128, 8), 256, 0, stream>>>(x, xu_p);
    modw_kernel<<<dim3(512), 256, 0, stream>>>(w1, sbuf, wm);
    conv_kernel<1><<<dim3(1024), 256, 0, stream>>>(xu_p, wm, nullptr, y1_p);
    modw_kernel<<<dim3(512), 256, 0, stream>>>(w2, sbuf + 2048, wm);
    conv_kernel<2><<<dim3(1024), 256, 0, stream>>>(y1_p, wm, out, nullptr);
}